// Round 1
// baseline (349.051 us; speedup 1.0000x reference)
//
#include <hip/hip_runtime.h>

#define EDIM 256
#define TDIM 1024
#define NHEAD 8
#define HDIM 32
#define NBATCH 8

// ---------------------------------------------------------------------------
// Generic per-batch projection GEMM: C[b] = W (E x E) @ X[b] (E x T) + bias
// 64x64 output tile per workgroup, BK=16, 256 threads, 4x4 micro-tile/thread.
// ---------------------------------------------------------------------------
__global__ __launch_bounds__(256) void proj_gemm(
    const float* __restrict__ X, const float* __restrict__ W,
    const float* __restrict__ bias, float* __restrict__ C)
{
  const int b  = blockIdx.z;
  const int m0 = blockIdx.y * 64;
  const int n0 = blockIdx.x * 64;
  const int tid = threadIdx.x;

  __shared__ float As[16][64];   // As[k][m]  (W tile, transposed)
  __shared__ float Bs[16][64];   // Bs[k][n]  (X tile)

  const int tm = (tid >> 4) * 4;
  const int tn = (tid & 15) * 4;

  const int lm = tid >> 2;            // 0..63 : W tile row
  const int lk = (tid & 3) * 4;       // 0,4,8,12 : W tile k
  const int bk = tid >> 4;            // 0..15 : X tile k-row
  const int bn = (tid & 15) * 4;      // X tile col

  float acc[4][4] = {};

  const float* Xb = X + (size_t)b * EDIM * TDIM;

  for (int k0 = 0; k0 < EDIM; k0 += 16) {
    float4 w4 = *(const float4*)&W[(size_t)(m0 + lm) * EDIM + k0 + lk];
    As[lk + 0][lm] = w4.x;
    As[lk + 1][lm] = w4.y;
    As[lk + 2][lm] = w4.z;
    As[lk + 3][lm] = w4.w;
    *(float4*)&Bs[bk][bn] =
        *(const float4*)&Xb[(size_t)(k0 + bk) * TDIM + n0 + bn];
    __syncthreads();
#pragma unroll
    for (int kk = 0; kk < 16; ++kk) {
      float4 a4 = *(const float4*)&As[kk][tm];
      float4 b4 = *(const float4*)&Bs[kk][tn];
      const float av[4] = {a4.x, a4.y, a4.z, a4.w};
      const float bv[4] = {b4.x, b4.y, b4.z, b4.w};
#pragma unroll
      for (int i = 0; i < 4; ++i)
#pragma unroll
        for (int j = 0; j < 4; ++j)
          acc[i][j] += av[i] * bv[j];
    }
    __syncthreads();
  }

  float* Cb = C + (size_t)b * EDIM * TDIM;
#pragma unroll
  for (int i = 0; i < 4; ++i) {
    const float bi = bias[m0 + tm + i];
    float4 o4;
    o4.x = acc[i][0] + bi;
    o4.y = acc[i][1] + bi;
    o4.z = acc[i][2] + bi;
    o4.w = acc[i][3] + bi;
    *(float4*)&Cb[(size_t)(m0 + tm + i) * TDIM + n0 + tn] = o4;
  }
}

// ---------------------------------------------------------------------------
// Flash attention (fp32): one workgroup per (head-batch, 64-row Q tile).
// Streams 64-wide S tiles: S = scale*Q^T K + mask, online softmax (shuffle
// row-reductions over the 16 lanes owning a row), P through LDS, PV GEMM.
// qp/kp/vp layout: [B][E][T]  (head h of batch b = channels h*32..h*32+31).
// Writes ao in the same [B][E][T] layout for the output projection.
// ---------------------------------------------------------------------------
__global__ __launch_bounds__(256) void flash_attn(
    const float* __restrict__ qp, const float* __restrict__ kp,
    const float* __restrict__ vp, const float* __restrict__ mask,
    float* __restrict__ ao)
{
  const int tt = blockIdx.x;          // 16 query tiles
  const int bh = blockIdx.y;          // 64 head-batches
  const int b = bh >> 3, h = bh & 7;
  const int tid = threadIdx.x;
  const int t0 = tt * 64;

  __shared__ float Qs[HDIM][64];        // Qs[d][t]
  __shared__ float Ks[HDIM][64];        // Ks[d][s]
  __shared__ float Vs[64][HDIM + 2];    // Vs[s][d]  (+2 pad: aligned float2)
  __shared__ float Ps[64][65];          // Ps[s][t]
  __shared__ float Os[HDIM][64];        // Os[d][t]  (store transpose)

  const size_t hoff = ((size_t)b * EDIM + (size_t)h * HDIM) * TDIM;
  const float* qb = qp + hoff;
  const float* kb = kp + hoff;
  const float* vb = vp + hoff;

  // Q tile
  {
    const int dr = tid >> 4;
    const int tc = (tid & 15) * 4;
#pragma unroll
    for (int it = 0; it < 2; ++it) {
      const int d = it * 16 + dr;
      *(float4*)&Qs[d][tc] = *(const float4*)&qb[(size_t)d * TDIM + t0 + tc];
    }
  }

  const int tm = (tid >> 4) * 4;      // S-tile / O rows owned by this thread
  const int sn = (tid & 15) * 4;      // S-tile cols
  const int dO = (tid & 15) * 2;      // O cols

  float m_run[4], l_run[4];
  float accO[4][2] = {};
#pragma unroll
  for (int i = 0; i < 4; ++i) { m_run[i] = -1e30f; l_run[i] = 0.0f; }

  const float scale = 0.17677669529663687f;  // 32^-0.5

  for (int s0 = 0; s0 < TDIM; s0 += 64) {
    __syncthreads();   // previous PV done (and Q tile visible on iter 0)
    // K,V tiles
    {
      const int dr = tid >> 4;
      const int sc = (tid & 15) * 4;
#pragma unroll
      for (int it = 0; it < 2; ++it) {
        const int d = it * 16 + dr;
        *(float4*)&Ks[d][sc] = *(const float4*)&kb[(size_t)d * TDIM + s0 + sc];
        float4 v4 = *(const float4*)&vb[(size_t)d * TDIM + s0 + sc];
        Vs[sc + 0][d] = v4.x;
        Vs[sc + 1][d] = v4.y;
        Vs[sc + 2][d] = v4.z;
        Vs[sc + 3][d] = v4.w;
      }
    }
    __syncthreads();

    // S = scale * (Q^T K) + mask
    float sv[4][4];
    {
      float acc[4][4] = {};
#pragma unroll
      for (int d = 0; d < HDIM; ++d) {
        float4 a4 = *(const float4*)&Qs[d][tm];
        float4 b4 = *(const float4*)&Ks[d][sn];
        const float av[4] = {a4.x, a4.y, a4.z, a4.w};
        const float bv[4] = {b4.x, b4.y, b4.z, b4.w};
#pragma unroll
        for (int i = 0; i < 4; ++i)
#pragma unroll
          for (int j = 0; j < 4; ++j)
            acc[i][j] += av[i] * bv[j];
      }
#pragma unroll
      for (int i = 0; i < 4; ++i) {
        float4 mk = *(const float4*)&mask[(size_t)(t0 + tm + i) * TDIM + s0 + sn];
        sv[i][0] = acc[i][0] * scale + mk.x;
        sv[i][1] = acc[i][1] * scale + mk.y;
        sv[i][2] = acc[i][2] * scale + mk.z;
        sv[i][3] = acc[i][3] * scale + mk.w;
      }
    }

    // online softmax (rows tm..tm+3 are owned by 16 consecutive lanes)
#pragma unroll
    for (int i = 0; i < 4; ++i) {
      float lmx = fmaxf(fmaxf(sv[i][0], sv[i][1]), fmaxf(sv[i][2], sv[i][3]));
#pragma unroll
      for (int off = 1; off < 16; off <<= 1)
        lmx = fmaxf(lmx, __shfl_xor(lmx, off));
      const float m_new = fmaxf(m_run[i], lmx);
      const float alpha = __expf(m_run[i] - m_new);
      float rs = 0.0f;
#pragma unroll
      for (int j = 0; j < 4; ++j) {
        const float p = __expf(sv[i][j] - m_new);
        sv[i][j] = p;
        rs += p;
      }
#pragma unroll
      for (int off = 1; off < 16; off <<= 1)
        rs += __shfl_xor(rs, off);
      l_run[i] = l_run[i] * alpha + rs;
      m_run[i] = m_new;
      accO[i][0] *= alpha;
      accO[i][1] *= alpha;
    }

    // P^T into LDS
#pragma unroll
    for (int i = 0; i < 4; ++i)
#pragma unroll
      for (int j = 0; j < 4; ++j)
        Ps[sn + j][tm + i] = sv[i][j];

    __syncthreads();

    // O += P V   (thread owns rows tm..tm+3, cols dO..dO+1)
#pragma unroll 4
    for (int s = 0; s < 64; ++s) {
      const float p0 = Ps[s][tm + 0];
      const float p1 = Ps[s][tm + 1];
      const float p2 = Ps[s][tm + 2];
      const float p3 = Ps[s][tm + 3];
      const float2 vv = *(const float2*)&Vs[s][dO];
      accO[0][0] += p0 * vv.x; accO[0][1] += p0 * vv.y;
      accO[1][0] += p1 * vv.x; accO[1][1] += p1 * vv.y;
      accO[2][0] += p2 * vv.x; accO[2][1] += p2 * vv.y;
      accO[3][0] += p3 * vv.x; accO[3][1] += p3 * vv.y;
    }
  }

  // normalize, transpose through LDS, coalesced store: ao[d][t]
  __syncthreads();
#pragma unroll
  for (int i = 0; i < 4; ++i) {
    const float inv = 1.0f / l_run[i];
    Os[dO + 0][tm + i] = accO[i][0] * inv;
    Os[dO + 1][tm + i] = accO[i][1] * inv;
  }
  __syncthreads();
  {
    const int d  = tid >> 3;            // 0..31
    const int tc = (tid & 7) * 8;       // 0..56
    float* dst = ao + hoff + (size_t)d * TDIM + t0 + tc;
    *(float4*)&dst[0] = *(const float4*)&Os[d][tc];
    *(float4*)&dst[4] = *(const float4*)&Os[d][tc + 4];
  }
}

// ---------------------------------------------------------------------------
extern "C" void kernel_launch(void* const* d_in, const int* in_sizes, int n_in,
                              void* d_out, int out_size, void* d_ws, size_t ws_size,
                              hipStream_t stream)
{
  const float* q   = (const float*)d_in[0];
  const float* k   = (const float*)d_in[1];
  const float* v   = (const float*)d_in[2];
  const float* msk = (const float*)d_in[3];
  const float* Wq  = (const float*)d_in[4];
  const float* Wk  = (const float*)d_in[5];
  const float* Wv  = (const float*)d_in[6];
  const float* Wo  = (const float*)d_in[7];
  const float* bq  = (const float*)d_in[8];
  const float* bk  = (const float*)d_in[9];
  const float* bv  = (const float*)d_in[10];
  const float* bo  = (const float*)d_in[11];
  float* out = (float*)d_out;

  const size_t plane = (size_t)NBATCH * EDIM * TDIM;  // 2M floats = 8 MB
  float* qp = (float*)d_ws;
  float* kp = qp + plane;
  float* vp = kp + plane;
  float* aop = vp + plane;

  dim3 bb(256);
  dim3 gg(TDIM / 64, EDIM / 64, NBATCH);
  hipLaunchKernelGGL(proj_gemm, gg, bb, 0, stream, q, Wq, bq, qp);
  hipLaunchKernelGGL(proj_gemm, gg, bb, 0, stream, k, Wk, bk, kp);
  hipLaunchKernelGGL(proj_gemm, gg, bb, 0, stream, v, Wv, bv, vp);

  dim3 ga(TDIM / 64, NBATCH * NHEAD);
  hipLaunchKernelGGL(flash_attn, ga, bb, 0, stream, qp, kp, vp, msk, aop);

  hipLaunchKernelGGL(proj_gemm, gg, bb, 0, stream, aop, Wo, bo, out);
}

// Round 2
// 204.117 us; speedup vs baseline: 1.7101x; 1.7101x over previous
//
#include <hip/hip_runtime.h>

#define EDIM 256
#define TDIM 1024
#define NHEAD 8
#define HDIM 32
#define NBATCH 8

typedef __attribute__((ext_vector_type(8))) short short8;
typedef __attribute__((ext_vector_type(4))) short short4v;
typedef __attribute__((ext_vector_type(4))) float f32x4;

// round-to-nearest fp32 -> bf16 (as short)
__device__ __forceinline__ short f2bf(float x) {
  unsigned u = __float_as_uint(x);
  u = (u + 0x7fffu + ((u >> 16) & 1u)) >> 16;
  return (short)u;
}
__device__ __forceinline__ float bf2f(short h) {
  return __uint_as_float(((unsigned)(unsigned short)h) << 16);
}
// split x into bf16 hi + bf16 lo (x ~= hi + lo, residual ~2^-17 rel)
__device__ __forceinline__ void split4(float a, float b, float c, float d,
                                       short4v& h, short4v& l) {
  h[0] = f2bf(a); l[0] = f2bf(a - bf2f(h[0]));
  h[1] = f2bf(b); l[1] = f2bf(b - bf2f(h[1]));
  h[2] = f2bf(c); l[2] = f2bf(c - bf2f(h[2]));
  h[3] = f2bf(d); l[3] = f2bf(d - bf2f(h[3]));
}

__device__ __forceinline__ f32x4 mfma16(short8 a, short8 b, f32x4 c) {
  return __builtin_amdgcn_mfma_f32_16x16x32_bf16(a, b, c, 0, 0, 0);
}

// ---------------------------------------------------------------------------
// Projection GEMM via split-bf16 MFMA: C[b] = W (ExE) @ X[b] (ExT) + bias.
// Block tile 64m x 64n, BK=64, 256 threads (4 waves, wave w owns rows 16w..).
// A = W [m][k] staged directly; B = X staged transposed to [n][k] so B-frags
// are k-contiguous ds_read_b128. hi*hi + hi*lo + lo*hi (lo*lo dropped).
// ---------------------------------------------------------------------------
__global__ __launch_bounds__(256) void proj_mfma(
    const float* __restrict__ X, const float* __restrict__ W,
    const float* __restrict__ bias, float* __restrict__ C)
{
  const int b  = blockIdx.z;
  const int m0 = blockIdx.y * 64;
  const int n0 = blockIdx.x * 64;
  const int tid  = threadIdx.x;
  const int w    = tid >> 6;
  const int lane = tid & 63;
  const int quad = lane >> 4;
  const int l16  = lane & 15;

  __shared__ __align__(16) short Wbuf[2][64][72];  // [hi/lo][m][k] pad 72
  __shared__ __align__(16) short Xbuf[2][64][72];  // [hi/lo][n][k]

  const float* Xb = X + (size_t)b * EDIM * TDIM;

  f32x4 acc[4] = {};

  for (int k0 = 0; k0 < EDIM; k0 += 64) {
    __syncthreads();
    // stage W tile [m0..m0+63][k0..k0+63]
    {
      const int m  = tid >> 2;
      const int kq = (tid & 3) * 16;
      const float* src = &W[(size_t)(m0 + m) * EDIM + k0 + kq];
#pragma unroll
      for (int i = 0; i < 4; ++i) {
        float4 x4 = *(const float4*)&src[4 * i];
        short4v h, l;
        split4(x4.x, x4.y, x4.z, x4.w, h, l);
        *(short4v*)&Wbuf[0][m][kq + 4 * i] = h;
        *(short4v*)&Wbuf[1][m][kq + 4 * i] = l;
      }
    }
    // stage X tile transposed -> Xbuf[n][k] (reads coalesced along n)
    {
      const int n  = tid & 63;
      const int kq = (tid >> 6) * 4;
#pragma unroll
      for (int p = 0; p < 4; ++p) {
        const int kk = kq + 16 * p;
        short4v h, l;
        float x0 = Xb[(size_t)(k0 + kk + 0) * TDIM + n0 + n];
        float x1 = Xb[(size_t)(k0 + kk + 1) * TDIM + n0 + n];
        float x2 = Xb[(size_t)(k0 + kk + 2) * TDIM + n0 + n];
        float x3 = Xb[(size_t)(k0 + kk + 3) * TDIM + n0 + n];
        split4(x0, x1, x2, x3, h, l);
        *(short4v*)&Xbuf[0][n][kk] = h;
        *(short4v*)&Xbuf[1][n][kk] = l;
      }
    }
    __syncthreads();

#pragma unroll
    for (int c = 0; c < 2; ++c) {
      short8 ahi = *(const short8*)&Wbuf[0][16 * w + l16][32 * c + quad * 8];
      short8 alo = *(const short8*)&Wbuf[1][16 * w + l16][32 * c + quad * 8];
#pragma unroll
      for (int j = 0; j < 4; ++j) {
        short8 bhi = *(const short8*)&Xbuf[0][16 * j + l16][32 * c + quad * 8];
        short8 blo = *(const short8*)&Xbuf[1][16 * j + l16][32 * c + quad * 8];
        acc[j] = mfma16(ahi, bhi, acc[j]);
        acc[j] = mfma16(ahi, blo, acc[j]);
        acc[j] = mfma16(alo, bhi, acc[j]);
      }
    }
  }

  float* Cb = C + (size_t)b * EDIM * TDIM;
#pragma unroll
  for (int r = 0; r < 4; ++r) {
    const int m = m0 + 16 * w + quad * 4 + r;
    const float bi = bias[m];
#pragma unroll
    for (int j = 0; j < 4; ++j)
      Cb[(size_t)m * TDIM + n0 + 16 * j + l16] = acc[j][r] + bi;
  }
}

// ---------------------------------------------------------------------------
// Flash attention via split-bf16 MFMA. Q tile = 128 rows; wave w owns rows
// 32w..32w+31 (two 16-row m-tiles). Per 64-wide S tile: S = scale*(Q K^T)
// (3-pass split MFMA) + fp32 mask; online softmax with 16-lane shuffle row
// reductions; P (plain bf16) through LDS into PV MFMAs (V split hi/lo).
// Output transposed through LDS (aliased over dead Q buffer) for coalesced
// [d][t] stores. qp/kp/vp/ao layout: [B][E][T].
// ---------------------------------------------------------------------------
__global__ __launch_bounds__(256) void flash_mfma(
    const float* __restrict__ qp, const float* __restrict__ kp,
    const float* __restrict__ vp, const float* __restrict__ mask,
    float* __restrict__ ao)
{
  const int bh = blockIdx.x;          // bh-fastest: blocks sharing mask rows
  const int t0 = blockIdx.y * 128;    // land together per XCD (L2 reuse)
  const int b = bh >> 3, h = bh & 7;
  const int tid  = threadIdx.x;
  const int w    = tid >> 6;
  const int lane = tid & 63;
  const int quad = lane >> 4;
  const int l16  = lane & 15;

  __shared__ __align__(16) short Qbuf[2][128][40];  // [hi/lo][t][d]
  __shared__ __align__(16) short Kbuf[2][64][40];   // [hi/lo][s][d]
  __shared__ __align__(16) short Vbuf[2][32][72];   // [hi/lo][d][s]
  __shared__ __align__(16) short Ps[128][72];       // bf16 P [t][s]

  const size_t hoff = ((size_t)b * EDIM + (size_t)h * HDIM) * TDIM;
  const float* qb = qp + hoff;
  const float* kb = kp + hoff;
  const float* vb = vp + hoff;

  // stage Q tile [t][d] (transpose from [d][t]; reads coalesced along t)
  {
    const int tl = tid & 127;
    const int d0 = (tid >> 7) * 4;
#pragma unroll
    for (int p = 0; p < 4; ++p) {
      const int db = d0 + 8 * p;
      short4v hh, ll;
      float x0 = qb[(size_t)(db + 0) * TDIM + t0 + tl];
      float x1 = qb[(size_t)(db + 1) * TDIM + t0 + tl];
      float x2 = qb[(size_t)(db + 2) * TDIM + t0 + tl];
      float x3 = qb[(size_t)(db + 3) * TDIM + t0 + tl];
      split4(x0, x1, x2, x3, hh, ll);
      *(short4v*)&Qbuf[0][tl][db] = hh;
      *(short4v*)&Qbuf[1][tl][db] = ll;
    }
  }
  __syncthreads();

  // Q fragments live in registers for the whole kernel
  short8 qh[2], ql[2];
#pragma unroll
  for (int mt = 0; mt < 2; ++mt) {
    qh[mt] = *(const short8*)&Qbuf[0][32 * w + 16 * mt + l16][quad * 8];
    ql[mt] = *(const short8*)&Qbuf[1][32 * w + 16 * mt + l16][quad * 8];
  }

  float m_run[2][4], l_run[2][4];
  f32x4 oacc[2][2] = {};  // [mt][nt]
#pragma unroll
  for (int mt = 0; mt < 2; ++mt)
#pragma unroll
    for (int r = 0; r < 4; ++r) { m_run[mt][r] = -1e30f; l_run[mt][r] = 0.f; }

  const float scale = 0.17677669529663687f;  // 32^-0.5

  for (int s0 = 0; s0 < TDIM; s0 += 64) {
    __syncthreads();  // prior iter's K/V/Ps reads complete before restage
    // stage K [s][d]
    {
      const int sl = tid & 63;
      const int d0 = (tid >> 6) * 4;
#pragma unroll
      for (int p = 0; p < 2; ++p) {
        const int db = d0 + 16 * p;
        short4v hh, ll;
        float x0 = kb[(size_t)(db + 0) * TDIM + s0 + sl];
        float x1 = kb[(size_t)(db + 1) * TDIM + s0 + sl];
        float x2 = kb[(size_t)(db + 2) * TDIM + s0 + sl];
        float x3 = kb[(size_t)(db + 3) * TDIM + s0 + sl];
        split4(x0, x1, x2, x3, hh, ll);
        *(short4v*)&Kbuf[0][sl][db] = hh;
        *(short4v*)&Kbuf[1][sl][db] = ll;
      }
    }
    // stage V [d][s] (source is [d][t]-major: direct, coalesced)
    {
      const int d  = tid >> 3;
      const int sq = (tid & 7) * 8;
#pragma unroll
      for (int p = 0; p < 2; ++p) {
        float4 x4 = *(const float4*)&vb[(size_t)d * TDIM + s0 + sq + 4 * p];
        short4v hh, ll;
        split4(x4.x, x4.y, x4.z, x4.w, hh, ll);
        *(short4v*)&Vbuf[0][d][sq + 4 * p] = hh;
        *(short4v*)&Vbuf[1][d][sq + 4 * p] = ll;
      }
    }
    __syncthreads();

#pragma unroll
    for (int mt = 0; mt < 2; ++mt) {
      // mask prefetch (16-lane contiguous 64B segments, L2-resident)
      float mk[4][4];
#pragma unroll
      for (int j = 0; j < 4; ++j)
#pragma unroll
        for (int r = 0; r < 4; ++r)
          mk[j][r] = mask[(size_t)(t0 + 32 * w + 16 * mt + quad * 4 + r) * TDIM
                          + s0 + 16 * j + l16];

      // S tile: 4 col-tiles, 3-pass split MFMA each
      f32x4 sc[4] = {};
#pragma unroll
      for (int j = 0; j < 4; ++j) {
        short8 kh = *(const short8*)&Kbuf[0][16 * j + l16][quad * 8];
        short8 kl = *(const short8*)&Kbuf[1][16 * j + l16][quad * 8];
        sc[j] = mfma16(qh[mt], kh, sc[j]);
        sc[j] = mfma16(qh[mt], kl, sc[j]);
        sc[j] = mfma16(ql[mt], kh, sc[j]);
      }
      float pj[4][4];
#pragma unroll
      for (int j = 0; j < 4; ++j)
#pragma unroll
        for (int r = 0; r < 4; ++r)
          pj[j][r] = sc[j][r] * scale + mk[j][r];

      // online softmax; row r lives on the 16 lanes sharing quad-group
#pragma unroll
      for (int r = 0; r < 4; ++r) {
        float mx = fmaxf(fmaxf(pj[0][r], pj[1][r]), fmaxf(pj[2][r], pj[3][r]));
        mx = fmaxf(mx, __shfl_xor(mx, 1));
        mx = fmaxf(mx, __shfl_xor(mx, 2));
        mx = fmaxf(mx, __shfl_xor(mx, 4));
        mx = fmaxf(mx, __shfl_xor(mx, 8));
        const float mnew  = fmaxf(m_run[mt][r], mx);
        const float alpha = __expf(m_run[mt][r] - mnew);
        m_run[mt][r] = mnew;
        float rs = 0.f;
#pragma unroll
        for (int j = 0; j < 4; ++j) {
          const float p = __expf(pj[j][r] - mnew);
          pj[j][r] = p;
          rs += p;
        }
        rs += __shfl_xor(rs, 1);
        rs += __shfl_xor(rs, 2);
        rs += __shfl_xor(rs, 4);
        rs += __shfl_xor(rs, 8);
        l_run[mt][r] = l_run[mt][r] * alpha + rs;
        oacc[mt][0][r] *= alpha;
        oacc[mt][1][r] *= alpha;
      }

      // P (bf16) -> LDS in [t][s]; C-layout -> A-layout round trip
#pragma unroll
      for (int j = 0; j < 4; ++j)
#pragma unroll
        for (int r = 0; r < 4; ++r)
          Ps[32 * w + 16 * mt + quad * 4 + r][16 * j + l16] = f2bf(pj[j][r]);
    }
    __syncthreads();

    // O += P V
#pragma unroll
    for (int kc = 0; kc < 2; ++kc) {
      short8 vh[2], vl[2];
#pragma unroll
      for (int nt = 0; nt < 2; ++nt) {
        vh[nt] = *(const short8*)&Vbuf[0][16 * nt + l16][32 * kc + quad * 8];
        vl[nt] = *(const short8*)&Vbuf[1][16 * nt + l16][32 * kc + quad * 8];
      }
#pragma unroll
      for (int mt = 0; mt < 2; ++mt) {
        short8 pa = *(const short8*)&Ps[32 * w + 16 * mt + l16][32 * kc + quad * 8];
#pragma unroll
        for (int nt = 0; nt < 2; ++nt) {
          oacc[mt][nt] = mfma16(pa, vh[nt], oacc[mt][nt]);
          oacc[mt][nt] = mfma16(pa, vl[nt], oacc[mt][nt]);
        }
      }
    }
  }

  // epilogue: normalize, transpose through LDS (alias dead Q buffer), store
  __syncthreads();
  float (*Os)[136] = (float (*)[136]) & Qbuf[0][0][0];  // 32x136x4 B <= Qbuf
  {
    float inv[2][4];
#pragma unroll
    for (int mt = 0; mt < 2; ++mt)
#pragma unroll
      for (int r = 0; r < 4; ++r) inv[mt][r] = 1.f / l_run[mt][r];
#pragma unroll
    for (int nt = 0; nt < 2; ++nt)
#pragma unroll
      for (int mt = 0; mt < 2; ++mt)
#pragma unroll
        for (int r = 0; r < 4; ++r)
          Os[16 * nt + l16][32 * w + 16 * mt + quad * 4 + r] =
              oacc[mt][nt][r] * inv[mt][r];
  }
  __syncthreads();
  {
    const int d  = tid >> 3;
    const int tc = (tid & 7) * 16;
    float* dst = ao + hoff + (size_t)d * TDIM + t0 + tc;
#pragma unroll
    for (int i = 0; i < 4; ++i)
      *(float4*)&dst[4 * i] = *(const float4*)&Os[d][tc + 4 * i];
  }
}

// ---------------------------------------------------------------------------
extern "C" void kernel_launch(void* const* d_in, const int* in_sizes, int n_in,
                              void* d_out, int out_size, void* d_ws, size_t ws_size,
                              hipStream_t stream)
{
  const float* q   = (const float*)d_in[0];
  const float* k   = (const float*)d_in[1];
  const float* v   = (const float*)d_in[2];
  const float* msk = (const float*)d_in[3];
  const float* Wq  = (const float*)d_in[4];
  const float* Wk  = (const float*)d_in[5];
  const float* Wv  = (const float*)d_in[6];
  const float* Wo  = (const float*)d_in[7];
  const float* bq  = (const float*)d_in[8];
  const float* bk  = (const float*)d_in[9];
  const float* bv  = (const float*)d_in[10];
  const float* bo  = (const float*)d_in[11];
  float* out = (float*)d_out;

  const size_t plane = (size_t)NBATCH * EDIM * TDIM;  // 2M floats = 8 MB
  float* qp  = (float*)d_ws;
  float* kp  = qp + plane;
  float* vp  = kp + plane;
  float* aop = vp + plane;

  dim3 bb(256);
  dim3 gp(TDIM / 64, EDIM / 64, NBATCH);
  hipLaunchKernelGGL(proj_mfma, gp, bb, 0, stream, q, Wq, bq, qp);
  hipLaunchKernelGGL(proj_mfma, gp, bb, 0, stream, k, Wk, bk, kp);
  hipLaunchKernelGGL(proj_mfma, gp, bb, 0, stream, v, Wv, bv, vp);

  dim3 ga(NBATCH * NHEAD, TDIM / 128);
  hipLaunchKernelGGL(flash_mfma, ga, bb, 0, stream, qp, kp, vp, msk, aop);

  hipLaunchKernelGGL(proj_mfma, gp, bb, 0, stream, aop, Wo, bo, out);
}